// Round 7
// baseline (135.777 us; speedup 1.0000x reference)
//
#include <hip/hip_runtime.h>

// R12: GRANULARITY CURVE, POINT 3. R11 (ITERS 8->2, 2048->8192 blocks) gave
// the first real win (-3us total): one-shot co-resident cohorts leave a long
// in-flight-decay drain tail; HW backfill of retiring blocks sustains request
// pressure. Continue the axis: ITERS 2->1, 16384 blocks (8 cohorts/CU).
// Per-block: 13 L2-hot table loads -> barrier -> 4KB load burst -> ~25
// VALU/elem -> 4KB NT-store burst -> retire. Everything else identical to R11.
// Decision rule: >=2us win -> keep pushing (block=128 next); neutral ->
// churn axis exhausted, declare empirical mixed-stream floor.

#define ITERS 1

typedef float floatx4 __attribute__((ext_vector_type(4)));

// ---------------------------------------------------------------------------
// Kernel 1: one wave computes the tiny MLP -> knot vector -> per-interval
// cubic coefficients (centered at s = xp - t[k]) and writes to workspace:
//   ws[0..27]  = 7 x float4 coefficient table
//   ws[28..33] = 6 interior decision knots (t4..t9)
// ---------------------------------------------------------------------------
__global__ __launch_bounds__(64) void nsff_table_kernel(
    float* __restrict__ ws,
    const float* __restrict__ a,
    const float* __restrict__ W1, const float* __restrict__ b1,
    const float* __restrict__ W2, const float* __restrict__ b2,
    const float* __restrict__ Ww, const float* __restrict__ bw,
    const float* __restrict__ Wk, const float* __restrict__ bk) {
    __shared__ float net1[32];
    __shared__ float net2[32];
    __shared__ float w9s[9];
    __shared__ float kraws[7];
    __shared__ float tsh[14];
    __shared__ float w10s[10];

    const int tid = threadIdx.x;  // single wave: same-wave LDS ops are ordered,
                                  // no barriers needed (R6-proven structure)
    if (tid < 32) net1[tid] = sinf(a[0] * W1[tid] + b1[tid]);
    if (tid < 32) {
        float s = b2[tid];
#pragma unroll 16
        for (int j = 0; j < 32; ++j) s += net1[j] * W2[j * 32 + tid];
        net2[tid] = sinf(s);
    }
    if (tid < 9) {
        float s = bw[tid];
#pragma unroll
        for (int j = 0; j < 32; ++j) s += net2[j] * Ww[j * 9 + tid];
        w9s[tid] = s;
    } else if (tid >= 16 && tid < 23) {
        const int i = tid - 16;
        float s = bk[i];
#pragma unroll
        for (int j = 0; j < 32; ++j) s += net2[j] * Wk[j * 7 + i];
        kraws[i] = s;
    }
    if (tid == 0) {
        // softmax (max-subtracted) -> cumsum -> knot vector
        float mx = kraws[0];
        for (int i = 1; i < 7; ++i) mx = fmaxf(mx, kraws[i]);
        float e[7], sum = 0.f;
        for (int i = 0; i < 7; ++i) { e[i] = expf(kraws[i] - mx); sum += e[i]; }
        const float invsum = 1.f / sum;
        tsh[0] = tsh[1] = tsh[2] = tsh[3] = 0.f;
        float cs = 0.f;
        for (int i = 0; i < 7; ++i) { cs += e[i] * invsum; tsh[4 + i] = cs; }
        tsh[11] = tsh[12] = tsh[13] = 1.f;
        w10s[0] = 0.f;
        for (int i = 0; i < 9; ++i) w10s[1 + i] = w9s[i];
        for (int i = 0; i < 6; ++i) ws[28 + i] = tsh[4 + i];  // decision knots
    }
    if (tid < 7) {
        // Symbolic de Boor expansion for interval k = tid+3 in s = xp - t[k].
        const int k = tid + 3;
        float d[4][4];
        for (int j = 0; j < 4; ++j) {
            d[j][0] = w10s[k - 3 + j];
            d[j][1] = 0.f; d[j][2] = 0.f; d[j][3] = 0.f;
        }
        for (int r = 1; r <= 3; ++r) {
            for (int j = 3; j >= r; --j) {
                const float t0 = tsh[j + k - 3];
                const float t1 = tsh[j + 1 + k - r];
                const float den = t1 - t0;
                const float invd = (den != 0.f) ? (1.f / den) : 0.f;  // no NaN from degenerate intervals
                const float a0_ = (tsh[k] - t0) * invd;
                float nd[4];
                for (int i = 0; i < 4; ++i) nd[i] = d[j - 1][i] + a0_ * (d[j][i] - d[j - 1][i]);
                for (int i = 0; i < 3; ++i) nd[i + 1] += invd * (d[j][i] - d[j - 1][i]);
                for (int i = 0; i < 4; ++i) d[j][i] = nd[i];
            }
        }
        ws[4 * tid + 0] = d[3][0];
        ws[4 * tid + 1] = d[3][1];
        ws[4 * tid + 2] = d[3][2];
        ws[4 * tid + 3] = d[3][3];
    }
}

// ---------------------------------------------------------------------------
// Kernel 2: pure streaming map. No MLP, no transcendentals, one cheap barrier.
// ---------------------------------------------------------------------------
__global__ __launch_bounds__(256) void nsff_main_kernel(
    const float4* __restrict__ x, float4* __restrict__ out,
    const float* __restrict__ ws) {
    __shared__ float4 tbl[7];
    __shared__ float csh[6];

    const int tid = threadIdx.x;
    // 13 tiny loads, L2/L3-hot after block 0; barrier drains ONLY these.
    if (tid < 7) tbl[tid] = reinterpret_cast<const float4*>(ws)[tid];
    if (tid >= 16 && tid < 22) csh[tid - 16] = ws[28 + (tid - 16)];
    __syncthreads();

    const int stride = gridDim.x * 256;
    const int base = blockIdx.x * 256 + tid;

    // Issue all ITERS x loads; per-use vmcnt in the loop below streams them.
    float4 xv[ITERS];
#pragma unroll
    for (int it = 0; it < ITERS; ++it) xv[it] = x[base + it * stride];
    asm volatile("" ::: "memory");  // pin load issue point (R5 finding)

    float cs[6];
#pragma unroll
    for (int i = 0; i < 6; ++i) cs[i] = csh[i];

#pragma unroll
    for (int it = 0; it < ITERS; ++it) {
        floatx4 r;
#pragma unroll
        for (int c = 0; c < 4; ++c) {
            const float xi = (&xv[it].x)[c];
            const float xp = __builtin_amdgcn_fmed3f(
                xi * 0.57735026918962576f, 0.0f, 0.9999f);  // v_med3 clamp
            int kk = 0;
            float tk = 0.f;
#pragma unroll
            for (int i = 0; i < 6; ++i) {
                if (xp >= cs[i]) { kk = i + 1; tk = cs[i]; }
            }
            const float s = xp - tk;
            const float4 cf = tbl[kk];  // broadcast-heavy, conflict-free (measured 0)
            r[c] = fmaf(fmaf(fmaf(cf.w, s, cf.z), s, cf.y), s, cf.x);
        }
        __builtin_nontemporal_store(
            r, reinterpret_cast<floatx4*>(&out[base + it * stride]));  // NT stores (R9)
    }
}

// ---------------------------------------------------------------------------
// Fallback: fused single-kernel (used only if ws_size is too small).
// ---------------------------------------------------------------------------
__global__ __launch_bounds__(256) void nsff_fused_kernel(
    const float4* __restrict__ x, float4* __restrict__ out,
    const float* __restrict__ a,
    const float* __restrict__ W1, const float* __restrict__ b1,
    const float* __restrict__ W2, const float* __restrict__ b2,
    const float* __restrict__ Ww, const float* __restrict__ bw,
    const float* __restrict__ Wk, const float* __restrict__ bk) {
    __shared__ float net1[32];
    __shared__ float net2[32];
    __shared__ float w9s[9];
    __shared__ float kraws[7];
    __shared__ float tsh[14];
    __shared__ float w10s[10];
    __shared__ float4 tbl[7];
    __shared__ float csh[6];

    const int tid = threadIdx.x;
    const int stride = gridDim.x * 256;
    const int base = blockIdx.x * 256 + tid;

    float a0 = 0.f, w1v = 0.f, b1v = 0.f;
    if (tid < 32) { a0 = a[0]; w1v = W1[tid]; b1v = b1[tid]; }

    float4 xv[ITERS];
#pragma unroll
    for (int it = 0; it < ITERS; ++it) xv[it] = x[base + it * stride];
    asm volatile("" ::: "memory");

    if (tid < 32) net1[tid] = sinf(a0 * w1v + b1v);
    if (tid < 32) {
        float s = b2[tid];
#pragma unroll 16
        for (int j = 0; j < 32; ++j) s += net1[j] * W2[j * 32 + tid];
        net2[tid] = sinf(s);
    }
    if (tid < 9) {
        float s = bw[tid];
#pragma unroll
        for (int j = 0; j < 32; ++j) s += net2[j] * Ww[j * 9 + tid];
        w9s[tid] = s;
    } else if (tid >= 16 && tid < 23) {
        const int i = tid - 16;
        float s = bk[i];
#pragma unroll
        for (int j = 0; j < 32; ++j) s += net2[j] * Wk[j * 7 + i];
        kraws[i] = s;
    }
    if (tid == 0) {
        float mx = kraws[0];
        for (int i = 1; i < 7; ++i) mx = fmaxf(mx, kraws[i]);
        float e[7], sum = 0.f;
        for (int i = 0; i < 7; ++i) { e[i] = expf(kraws[i] - mx); sum += e[i]; }
        const float invsum = 1.f / sum;
        tsh[0] = tsh[1] = tsh[2] = tsh[3] = 0.f;
        float cs = 0.f;
        for (int i = 0; i < 7; ++i) { cs += e[i] * invsum; tsh[4 + i] = cs; }
        tsh[11] = tsh[12] = tsh[13] = 1.f;
        w10s[0] = 0.f;
        for (int i = 0; i < 9; ++i) w10s[1 + i] = w9s[i];
        for (int i = 0; i < 6; ++i) csh[i] = tsh[4 + i];
    }
    if (tid < 7) {
        const int k = tid + 3;
        float d[4][4];
        for (int j = 0; j < 4; ++j) {
            d[j][0] = w10s[k - 3 + j];
            d[j][1] = 0.f; d[j][2] = 0.f; d[j][3] = 0.f;
        }
        for (int r = 1; r <= 3; ++r) {
            for (int j = 3; j >= r; --j) {
                const float t0 = tsh[j + k - 3];
                const float t1 = tsh[j + 1 + k - r];
                const float den = t1 - t0;
                const float invd = (den != 0.f) ? (1.f / den) : 0.f;
                const float a0_ = (tsh[k] - t0) * invd;
                float nd[4];
                for (int i = 0; i < 4; ++i) nd[i] = d[j - 1][i] + a0_ * (d[j][i] - d[j - 1][i]);
                for (int i = 0; i < 3; ++i) nd[i + 1] += invd * (d[j][i] - d[j - 1][i]);
                for (int i = 0; i < 4; ++i) d[j][i] = nd[i];
            }
        }
        tbl[tid] = make_float4(d[3][0], d[3][1], d[3][2], d[3][3]);
    }
    __syncthreads();

    float cs[6];
#pragma unroll
    for (int i = 0; i < 6; ++i) cs[i] = csh[i];

#pragma unroll
    for (int it = 0; it < ITERS; ++it) {
        floatx4 r;
#pragma unroll
        for (int c = 0; c < 4; ++c) {
            const float xi = (&xv[it].x)[c];
            const float xp = __builtin_amdgcn_fmed3f(
                xi * 0.57735026918962576f, 0.0f, 0.9999f);
            int kk = 0;
            float tk = 0.f;
#pragma unroll
            for (int i = 0; i < 6; ++i) {
                if (xp >= cs[i]) { kk = i + 1; tk = cs[i]; }
            }
            const float s = xp - tk;
            const float4 cf = tbl[kk];
            r[c] = fmaf(fmaf(fmaf(cf.w, s, cf.z), s, cf.y), s, cf.x);
        }
        __builtin_nontemporal_store(
            r, reinterpret_cast<floatx4*>(&out[base + it * stride]));
    }
}

extern "C" void kernel_launch(void* const* d_in, const int* in_sizes, int n_in,
                              void* d_out, int out_size, void* d_ws, size_t ws_size,
                              hipStream_t stream) {
    const float* x  = (const float*)d_in[0];
    const float* a  = (const float*)d_in[1];
    const float* W1 = (const float*)d_in[2];
    const float* b1 = (const float*)d_in[3];
    const float* W2 = (const float*)d_in[4];
    const float* b2 = (const float*)d_in[5];
    const float* Ww = (const float*)d_in[6];
    const float* bw = (const float*)d_in[7];
    const float* Wk = (const float*)d_in[8];
    const float* bk = (const float*)d_in[9];
    float* out = (float*)d_out;

    const int n4 = out_size / 4;           // 256^3/4 = 4,194,304
    const int blocks = n4 / (256 * ITERS); // = 16384 (8 cohorts/CU, HW backfill)

    if (d_ws != nullptr && ws_size >= 34 * sizeof(float)) {
        float* ws = (float*)d_ws;
        nsff_table_kernel<<<1, 64, 0, stream>>>(ws, a, W1, b1, W2, b2,
                                                Ww, bw, Wk, bk);
        nsff_main_kernel<<<blocks, 256, 0, stream>>>((const float4*)x,
                                                     (float4*)out, ws);
    } else {
        nsff_fused_kernel<<<blocks, 256, 0, stream>>>((const float4*)x,
                                                      (float4*)out, a, W1, b1,
                                                      W2, b2, Ww, bw, Wk, bk);
    }
}

// Round 8
// 127.469 us; speedup vs baseline: 1.0652x; 1.0652x over previous
//
#include <hip/hip_runtime.h>

// R13: ITERS=2 (proven optimum of the R11/R12 granularity curve: 8->132-134,
// 2->129.1, 1->135.8) + ZERO per-block overhead. R12 proved per-block fixed
// cost (13 table loads + __syncthreads coupling 4 waves) is a real term at
// high block counts. This round removes it entirely:
//  - knots cs[6]: thread-uniform address -> s_load SGPR broadcast, no LDS.
//  - coeff table: per-WAVE LDS copy (lanes 0-27 ds_write ws[lane]); same-wave
//    DS ops are ordered at the LDS (R6-proven) -> NO __syncthreads in the
//    kernel at all. Waves are fully independent; retire/backfill churn at
//    wave granularity.
// Kept: split table kernel (R10), NT stores (R9), x loads issued at top (R5/6).

#define ITERS 2

typedef float floatx4 __attribute__((ext_vector_type(4)));

// ---------------------------------------------------------------------------
// Kernel 1: one wave computes the tiny MLP -> knot vector -> per-interval
// cubic coefficients (centered at s = xp - t[k]) and writes to workspace:
//   ws[0..27]  = 7 x float4 coefficient table
//   ws[28..33] = 6 interior decision knots (t4..t9)
// ---------------------------------------------------------------------------
__global__ __launch_bounds__(64) void nsff_table_kernel(
    float* __restrict__ ws,
    const float* __restrict__ a,
    const float* __restrict__ W1, const float* __restrict__ b1,
    const float* __restrict__ W2, const float* __restrict__ b2,
    const float* __restrict__ Ww, const float* __restrict__ bw,
    const float* __restrict__ Wk, const float* __restrict__ bk) {
    __shared__ float net1[32];
    __shared__ float net2[32];
    __shared__ float w9s[9];
    __shared__ float kraws[7];
    __shared__ float tsh[14];
    __shared__ float w10s[10];

    const int tid = threadIdx.x;  // single wave: same-wave LDS ops are ordered,
                                  // no barriers needed (R6-proven structure)
    if (tid < 32) net1[tid] = sinf(a[0] * W1[tid] + b1[tid]);
    if (tid < 32) {
        float s = b2[tid];
#pragma unroll 16
        for (int j = 0; j < 32; ++j) s += net1[j] * W2[j * 32 + tid];
        net2[tid] = sinf(s);
    }
    if (tid < 9) {
        float s = bw[tid];
#pragma unroll
        for (int j = 0; j < 32; ++j) s += net2[j] * Ww[j * 9 + tid];
        w9s[tid] = s;
    } else if (tid >= 16 && tid < 23) {
        const int i = tid - 16;
        float s = bk[i];
#pragma unroll
        for (int j = 0; j < 32; ++j) s += net2[j] * Wk[j * 7 + i];
        kraws[i] = s;
    }
    if (tid == 0) {
        // softmax (max-subtracted) -> cumsum -> knot vector
        float mx = kraws[0];
        for (int i = 1; i < 7; ++i) mx = fmaxf(mx, kraws[i]);
        float e[7], sum = 0.f;
        for (int i = 0; i < 7; ++i) { e[i] = expf(kraws[i] - mx); sum += e[i]; }
        const float invsum = 1.f / sum;
        tsh[0] = tsh[1] = tsh[2] = tsh[3] = 0.f;
        float cs = 0.f;
        for (int i = 0; i < 7; ++i) { cs += e[i] * invsum; tsh[4 + i] = cs; }
        tsh[11] = tsh[12] = tsh[13] = 1.f;
        w10s[0] = 0.f;
        for (int i = 0; i < 9; ++i) w10s[1 + i] = w9s[i];
        for (int i = 0; i < 6; ++i) ws[28 + i] = tsh[4 + i];  // decision knots
    }
    if (tid < 7) {
        // Symbolic de Boor expansion for interval k = tid+3 in s = xp - t[k].
        const int k = tid + 3;
        float d[4][4];
        for (int j = 0; j < 4; ++j) {
            d[j][0] = w10s[k - 3 + j];
            d[j][1] = 0.f; d[j][2] = 0.f; d[j][3] = 0.f;
        }
        for (int r = 1; r <= 3; ++r) {
            for (int j = 3; j >= r; --j) {
                const float t0 = tsh[j + k - 3];
                const float t1 = tsh[j + 1 + k - r];
                const float den = t1 - t0;
                const float invd = (den != 0.f) ? (1.f / den) : 0.f;  // no NaN from degenerate intervals
                const float a0_ = (tsh[k] - t0) * invd;
                float nd[4];
                for (int i = 0; i < 4; ++i) nd[i] = d[j - 1][i] + a0_ * (d[j][i] - d[j - 1][i]);
                for (int i = 0; i < 3; ++i) nd[i + 1] += invd * (d[j][i] - d[j - 1][i]);
                for (int i = 0; i < 4; ++i) d[j][i] = nd[i];
            }
        }
        ws[4 * tid + 0] = d[3][0];
        ws[4 * tid + 1] = d[3][1];
        ws[4 * tid + 2] = d[3][2];
        ws[4 * tid + 3] = d[3][3];
    }
}

// ---------------------------------------------------------------------------
// Kernel 2: pure streaming map. No MLP, no barrier, per-wave LDS table.
// ---------------------------------------------------------------------------
__global__ __launch_bounds__(256) void nsff_main_kernel(
    const float4* __restrict__ x, float4* __restrict__ out,
    const float* __restrict__ ws) {
    __shared__ float tblw[4 * 28];  // one 7-float4 table copy PER WAVE

    const int tid = threadIdx.x;
    const int wid = tid >> 6;
    const int lane = tid & 63;

    const int stride = gridDim.x * 256;
    const int base = blockIdx.x * 256 + tid;

    // Issue x loads first: they stream while the table setup resolves.
    float4 xv[ITERS];
#pragma unroll
    for (int it = 0; it < ITERS; ++it) xv[it] = x[base + it * stride];
    asm volatile("" ::: "memory");  // pin load issue point (R5 finding)

    // Per-wave table copy: lanes 0-27 each stage one dword. Same-wave
    // ds_write -> ds_read is ordered at the LDS: NO block barrier needed.
    if (lane < 28) tblw[wid * 28 + lane] = ws[lane];
    const float4* tbl = reinterpret_cast<const float4*>(&tblw[wid * 28]);

    // Knots: thread-uniform address -> s_load SGPR broadcast (no LDS).
    float cs[6];
#pragma unroll
    for (int i = 0; i < 6; ++i) cs[i] = ws[28 + i];

#pragma unroll
    for (int it = 0; it < ITERS; ++it) {
        floatx4 r;
#pragma unroll
        for (int c = 0; c < 4; ++c) {
            const float xi = (&xv[it].x)[c];
            const float xp = __builtin_amdgcn_fmed3f(
                xi * 0.57735026918962576f, 0.0f, 0.9999f);  // v_med3 clamp
            int kk = 0;
            float tk = 0.f;
#pragma unroll
            for (int i = 0; i < 6; ++i) {
                if (xp >= cs[i]) { kk = i + 1; tk = cs[i]; }
            }
            const float s = xp - tk;
            const float4 cf = tbl[kk];  // broadcast-heavy, conflict-free (measured 0)
            r[c] = fmaf(fmaf(fmaf(cf.w, s, cf.z), s, cf.y), s, cf.x);
        }
        __builtin_nontemporal_store(
            r, reinterpret_cast<floatx4*>(&out[base + it * stride]));  // NT stores (R9)
    }
}

// ---------------------------------------------------------------------------
// Fallback: fused single-kernel (used only if ws_size is too small).
// ---------------------------------------------------------------------------
__global__ __launch_bounds__(256) void nsff_fused_kernel(
    const float4* __restrict__ x, float4* __restrict__ out,
    const float* __restrict__ a,
    const float* __restrict__ W1, const float* __restrict__ b1,
    const float* __restrict__ W2, const float* __restrict__ b2,
    const float* __restrict__ Ww, const float* __restrict__ bw,
    const float* __restrict__ Wk, const float* __restrict__ bk) {
    __shared__ float net1[32];
    __shared__ float net2[32];
    __shared__ float w9s[9];
    __shared__ float kraws[7];
    __shared__ float tsh[14];
    __shared__ float w10s[10];
    __shared__ float4 tbl[7];
    __shared__ float csh[6];

    const int tid = threadIdx.x;
    const int stride = gridDim.x * 256;
    const int base = blockIdx.x * 256 + tid;

    float a0 = 0.f, w1v = 0.f, b1v = 0.f;
    if (tid < 32) { a0 = a[0]; w1v = W1[tid]; b1v = b1[tid]; }

    float4 xv[ITERS];
#pragma unroll
    for (int it = 0; it < ITERS; ++it) xv[it] = x[base + it * stride];
    asm volatile("" ::: "memory");

    if (tid < 32) net1[tid] = sinf(a0 * w1v + b1v);
    if (tid < 32) {
        float s = b2[tid];
#pragma unroll 16
        for (int j = 0; j < 32; ++j) s += net1[j] * W2[j * 32 + tid];
        net2[tid] = sinf(s);
    }
    if (tid < 9) {
        float s = bw[tid];
#pragma unroll
        for (int j = 0; j < 32; ++j) s += net2[j] * Ww[j * 9 + tid];
        w9s[tid] = s;
    } else if (tid >= 16 && tid < 23) {
        const int i = tid - 16;
        float s = bk[i];
#pragma unroll
        for (int j = 0; j < 32; ++j) s += net2[j] * Wk[j * 7 + i];
        kraws[i] = s;
    }
    if (tid == 0) {
        float mx = kraws[0];
        for (int i = 1; i < 7; ++i) mx = fmaxf(mx, kraws[i]);
        float e[7], sum = 0.f;
        for (int i = 0; i < 7; ++i) { e[i] = expf(kraws[i] - mx); sum += e[i]; }
        const float invsum = 1.f / sum;
        tsh[0] = tsh[1] = tsh[2] = tsh[3] = 0.f;
        float cs = 0.f;
        for (int i = 0; i < 7; ++i) { cs += e[i] * invsum; tsh[4 + i] = cs; }
        tsh[11] = tsh[12] = tsh[13] = 1.f;
        w10s[0] = 0.f;
        for (int i = 0; i < 9; ++i) w10s[1 + i] = w9s[i];
        for (int i = 0; i < 6; ++i) csh[i] = tsh[4 + i];
    }
    if (tid < 7) {
        const int k = tid + 3;
        float d[4][4];
        for (int j = 0; j < 4; ++j) {
            d[j][0] = w10s[k - 3 + j];
            d[j][1] = 0.f; d[j][2] = 0.f; d[j][3] = 0.f;
        }
        for (int r = 1; r <= 3; ++r) {
            for (int j = 3; j >= r; --j) {
                const float t0 = tsh[j + k - 3];
                const float t1 = tsh[j + 1 + k - r];
                const float den = t1 - t0;
                const float invd = (den != 0.f) ? (1.f / den) : 0.f;
                const float a0_ = (tsh[k] - t0) * invd;
                float nd[4];
                for (int i = 0; i < 4; ++i) nd[i] = d[j - 1][i] + a0_ * (d[j][i] - d[j - 1][i]);
                for (int i = 0; i < 3; ++i) nd[i + 1] += invd * (d[j][i] - d[j - 1][i]);
                for (int i = 0; i < 4; ++i) d[j][i] = nd[i];
            }
        }
        tbl[tid] = make_float4(d[3][0], d[3][1], d[3][2], d[3][3]);
    }
    __syncthreads();

    float cs[6];
#pragma unroll
    for (int i = 0; i < 6; ++i) cs[i] = csh[i];

#pragma unroll
    for (int it = 0; it < ITERS; ++it) {
        floatx4 r;
#pragma unroll
        for (int c = 0; c < 4; ++c) {
            const float xi = (&xv[it].x)[c];
            const float xp = __builtin_amdgcn_fmed3f(
                xi * 0.57735026918962576f, 0.0f, 0.9999f);
            int kk = 0;
            float tk = 0.f;
#pragma unroll
            for (int i = 0; i < 6; ++i) {
                if (xp >= cs[i]) { kk = i + 1; tk = cs[i]; }
            }
            const float s = xp - tk;
            const float4 cf = tbl[kk];
            r[c] = fmaf(fmaf(fmaf(cf.w, s, cf.z), s, cf.y), s, cf.x);
        }
        __builtin_nontemporal_store(
            r, reinterpret_cast<floatx4*>(&out[base + it * stride]));
    }
}

extern "C" void kernel_launch(void* const* d_in, const int* in_sizes, int n_in,
                              void* d_out, int out_size, void* d_ws, size_t ws_size,
                              hipStream_t stream) {
    const float* x  = (const float*)d_in[0];
    const float* a  = (const float*)d_in[1];
    const float* W1 = (const float*)d_in[2];
    const float* b1 = (const float*)d_in[3];
    const float* W2 = (const float*)d_in[4];
    const float* b2 = (const float*)d_in[5];
    const float* Ww = (const float*)d_in[6];
    const float* bw = (const float*)d_in[7];
    const float* Wk = (const float*)d_in[8];
    const float* bk = (const float*)d_in[9];
    float* out = (float*)d_out;

    const int n4 = out_size / 4;           // 256^3/4 = 4,194,304
    const int blocks = n4 / (256 * ITERS); // = 8192 (proven optimum, R11)

    if (d_ws != nullptr && ws_size >= 34 * sizeof(float)) {
        float* ws = (float*)d_ws;
        nsff_table_kernel<<<1, 64, 0, stream>>>(ws, a, W1, b1, W2, b2,
                                                Ww, bw, Wk, bk);
        nsff_main_kernel<<<blocks, 256, 0, stream>>>((const float4*)x,
                                                     (float4*)out, ws);
    } else {
        nsff_fused_kernel<<<blocks, 256, 0, stream>>>((const float4*)x,
                                                      (float4*)out, a, W1, b1,
                                                      W2, b2, Ww, bw, Wk, bk);
    }
}

// Round 9
// 127.406 us; speedup vs baseline: 1.0657x; 1.0005x over previous
//
#include <hip/hip_runtime.h>

// R14: PERSISTENT PIPELINED STREAM. Ladder: 134.6 (R5) -> 129.1 (R11 churn,
// ITERS=2/8192 blocks) -> 127.5 (R13 zero-sync per-wave tables). Both wins
// came from sustaining memory request generation. This round goes to the
// structural endpoint (the shape the 6.4TB/s fill kernels in this trace use):
// 2048 persistent blocks (8/CU), each thread loops over 8 chunks with 2-deep
// prefetch -> every wave issues a fresh load EVERY iteration; no block
// retire/dispatch gaps; request pressure constant until the last 2 chunks.
// Per-block table setup paid 2048x (was 8192x). Compute/access pattern/NT
// stores identical to R13.
// Decision rule: win -> refine (prefetch depth); neutral -> issue-pressure
// axis exhausted, declare empirical ceiling.

#define CHUNKS 8

typedef float floatx4 __attribute__((ext_vector_type(4)));

// ---------------------------------------------------------------------------
// Kernel 1: one wave computes the tiny MLP -> knot vector -> per-interval
// cubic coefficients (centered at s = xp - t[k]) and writes to workspace:
//   ws[0..27]  = 7 x float4 coefficient table
//   ws[28..33] = 6 interior decision knots (t4..t9)
// ---------------------------------------------------------------------------
__global__ __launch_bounds__(64) void nsff_table_kernel(
    float* __restrict__ ws,
    const float* __restrict__ a,
    const float* __restrict__ W1, const float* __restrict__ b1,
    const float* __restrict__ W2, const float* __restrict__ b2,
    const float* __restrict__ Ww, const float* __restrict__ bw,
    const float* __restrict__ Wk, const float* __restrict__ bk) {
    __shared__ float net1[32];
    __shared__ float net2[32];
    __shared__ float w9s[9];
    __shared__ float kraws[7];
    __shared__ float tsh[14];
    __shared__ float w10s[10];

    const int tid = threadIdx.x;  // single wave: same-wave LDS ops are ordered,
                                  // no barriers needed (R6-proven structure)
    if (tid < 32) net1[tid] = sinf(a[0] * W1[tid] + b1[tid]);
    if (tid < 32) {
        float s = b2[tid];
#pragma unroll 16
        for (int j = 0; j < 32; ++j) s += net1[j] * W2[j * 32 + tid];
        net2[tid] = sinf(s);
    }
    if (tid < 9) {
        float s = bw[tid];
#pragma unroll
        for (int j = 0; j < 32; ++j) s += net2[j] * Ww[j * 9 + tid];
        w9s[tid] = s;
    } else if (tid >= 16 && tid < 23) {
        const int i = tid - 16;
        float s = bk[i];
#pragma unroll
        for (int j = 0; j < 32; ++j) s += net2[j] * Wk[j * 7 + i];
        kraws[i] = s;
    }
    if (tid == 0) {
        // softmax (max-subtracted) -> cumsum -> knot vector
        float mx = kraws[0];
        for (int i = 1; i < 7; ++i) mx = fmaxf(mx, kraws[i]);
        float e[7], sum = 0.f;
        for (int i = 0; i < 7; ++i) { e[i] = expf(kraws[i] - mx); sum += e[i]; }
        const float invsum = 1.f / sum;
        tsh[0] = tsh[1] = tsh[2] = tsh[3] = 0.f;
        float cs = 0.f;
        for (int i = 0; i < 7; ++i) { cs += e[i] * invsum; tsh[4 + i] = cs; }
        tsh[11] = tsh[12] = tsh[13] = 1.f;
        w10s[0] = 0.f;
        for (int i = 0; i < 9; ++i) w10s[1 + i] = w9s[i];
        for (int i = 0; i < 6; ++i) ws[28 + i] = tsh[4 + i];  // decision knots
    }
    if (tid < 7) {
        // Symbolic de Boor expansion for interval k = tid+3 in s = xp - t[k].
        const int k = tid + 3;
        float d[4][4];
        for (int j = 0; j < 4; ++j) {
            d[j][0] = w10s[k - 3 + j];
            d[j][1] = 0.f; d[j][2] = 0.f; d[j][3] = 0.f;
        }
        for (int r = 1; r <= 3; ++r) {
            for (int j = 3; j >= r; --j) {
                const float t0 = tsh[j + k - 3];
                const float t1 = tsh[j + 1 + k - r];
                const float den = t1 - t0;
                const float invd = (den != 0.f) ? (1.f / den) : 0.f;  // no NaN from degenerate intervals
                const float a0_ = (tsh[k] - t0) * invd;
                float nd[4];
                for (int i = 0; i < 4; ++i) nd[i] = d[j - 1][i] + a0_ * (d[j][i] - d[j - 1][i]);
                for (int i = 0; i < 3; ++i) nd[i + 1] += invd * (d[j][i] - d[j - 1][i]);
                for (int i = 0; i < 4; ++i) d[j][i] = nd[i];
            }
        }
        ws[4 * tid + 0] = d[3][0];
        ws[4 * tid + 1] = d[3][1];
        ws[4 * tid + 2] = d[3][2];
        ws[4 * tid + 3] = d[3][3];
    }
}

// ---------------------------------------------------------------------------
// Kernel 2: persistent pipelined streaming map. No barrier; per-wave LDS
// table (R13); 2-deep prefetch loop -> continuous per-wave load issue.
// ---------------------------------------------------------------------------
__global__ __launch_bounds__(256) void nsff_main_kernel(
    const float4* __restrict__ x, float4* __restrict__ out,
    const float* __restrict__ ws) {
    __shared__ float tblw[4 * 28];  // one 7-float4 table copy PER WAVE

    const int tid = threadIdx.x;
    const int wid = tid >> 6;
    const int lane = tid & 63;

    const int stride = gridDim.x * 256;       // 2048*256 = 524288 float4s
    const int base = blockIdx.x * 256 + tid;

    // Prime the pipeline: 2 loads in flight before any compute.
    float4 cur = x[base];
    float4 nxt = x[base + stride];

    // Per-wave table copy: lanes 0-27 each stage one dword. Same-wave
    // ds_write -> ds_read is ordered at the LDS: NO block barrier needed.
    if (lane < 28) tblw[wid * 28 + lane] = ws[lane];
    const float4* tbl = reinterpret_cast<const float4*>(&tblw[wid * 28]);

    // Knots: thread-uniform address -> s_load SGPR broadcast (no LDS).
    float cs[6];
#pragma unroll
    for (int i = 0; i < 6; ++i) cs[i] = ws[28 + i];

#pragma unroll
    for (int it = 0; it < CHUNKS; ++it) {
        // Issue chunk it+2's load NOW; it lands while we compute chunk it.
        float4 fol;
        if (it + 2 < CHUNKS) fol = x[base + (it + 2) * stride];

        floatx4 r;
#pragma unroll
        for (int c = 0; c < 4; ++c) {
            const float xi = (&cur.x)[c];
            const float xp = __builtin_amdgcn_fmed3f(
                xi * 0.57735026918962576f, 0.0f, 0.9999f);  // v_med3 clamp
            int kk = 0;
            float tk = 0.f;
#pragma unroll
            for (int i = 0; i < 6; ++i) {
                if (xp >= cs[i]) { kk = i + 1; tk = cs[i]; }
            }
            const float s = xp - tk;
            const float4 cf = tbl[kk];  // broadcast-heavy, conflict-free (measured 0)
            r[c] = fmaf(fmaf(fmaf(cf.w, s, cf.z), s, cf.y), s, cf.x);
        }
        __builtin_nontemporal_store(
            r, reinterpret_cast<floatx4*>(&out[base + it * stride]));  // NT stores (R9)

        cur = nxt;
        nxt = fol;
    }
}

// ---------------------------------------------------------------------------
// Fallback: fused single-kernel (used only if ws_size is too small).
// ---------------------------------------------------------------------------
__global__ __launch_bounds__(256) void nsff_fused_kernel(
    const float4* __restrict__ x, float4* __restrict__ out,
    const float* __restrict__ a,
    const float* __restrict__ W1, const float* __restrict__ b1,
    const float* __restrict__ W2, const float* __restrict__ b2,
    const float* __restrict__ Ww, const float* __restrict__ bw,
    const float* __restrict__ Wk, const float* __restrict__ bk) {
    __shared__ float net1[32];
    __shared__ float net2[32];
    __shared__ float w9s[9];
    __shared__ float kraws[7];
    __shared__ float tsh[14];
    __shared__ float w10s[10];
    __shared__ float4 tbl[7];
    __shared__ float csh[6];

    const int tid = threadIdx.x;
    const int stride = gridDim.x * 256;
    const int base = blockIdx.x * 256 + tid;

    float a0 = 0.f, w1v = 0.f, b1v = 0.f;
    if (tid < 32) { a0 = a[0]; w1v = W1[tid]; b1v = b1[tid]; }

    float4 xv[CHUNKS];
#pragma unroll
    for (int it = 0; it < CHUNKS; ++it) xv[it] = x[base + it * stride];
    asm volatile("" ::: "memory");

    if (tid < 32) net1[tid] = sinf(a0 * w1v + b1v);
    if (tid < 32) {
        float s = b2[tid];
#pragma unroll 16
        for (int j = 0; j < 32; ++j) s += net1[j] * W2[j * 32 + tid];
        net2[tid] = sinf(s);
    }
    if (tid < 9) {
        float s = bw[tid];
#pragma unroll
        for (int j = 0; j < 32; ++j) s += net2[j] * Ww[j * 9 + tid];
        w9s[tid] = s;
    } else if (tid >= 16 && tid < 23) {
        const int i = tid - 16;
        float s = bk[i];
#pragma unroll
        for (int j = 0; j < 32; ++j) s += net2[j] * Wk[j * 7 + i];
        kraws[i] = s;
    }
    if (tid == 0) {
        float mx = kraws[0];
        for (int i = 1; i < 7; ++i) mx = fmaxf(mx, kraws[i]);
        float e[7], sum = 0.f;
        for (int i = 0; i < 7; ++i) { e[i] = expf(kraws[i] - mx); sum += e[i]; }
        const float invsum = 1.f / sum;
        tsh[0] = tsh[1] = tsh[2] = tsh[3] = 0.f;
        float cs = 0.f;
        for (int i = 0; i < 7; ++i) { cs += e[i] * invsum; tsh[4 + i] = cs; }
        tsh[11] = tsh[12] = tsh[13] = 1.f;
        w10s[0] = 0.f;
        for (int i = 0; i < 9; ++i) w10s[1 + i] = w9s[i];
        for (int i = 0; i < 6; ++i) csh[i] = tsh[4 + i];
    }
    if (tid < 7) {
        const int k = tid + 3;
        float d[4][4];
        for (int j = 0; j < 4; ++j) {
            d[j][0] = w10s[k - 3 + j];
            d[j][1] = 0.f; d[j][2] = 0.f; d[j][3] = 0.f;
        }
        for (int r = 1; r <= 3; ++r) {
            for (int j = 3; j >= r; --j) {
                const float t0 = tsh[j + k - 3];
                const float t1 = tsh[j + 1 + k - r];
                const float den = t1 - t0;
                const float invd = (den != 0.f) ? (1.f / den) : 0.f;
                const float a0_ = (tsh[k] - t0) * invd;
                float nd[4];
                for (int i = 0; i < 4; ++i) nd[i] = d[j - 1][i] + a0_ * (d[j][i] - d[j - 1][i]);
                for (int i = 0; i < 3; ++i) nd[i + 1] += invd * (d[j][i] - d[j - 1][i]);
                for (int i = 0; i < 4; ++i) d[j][i] = nd[i];
            }
        }
        tbl[tid] = make_float4(d[3][0], d[3][1], d[3][2], d[3][3]);
    }
    __syncthreads();

    float cs[6];
#pragma unroll
    for (int i = 0; i < 6; ++i) cs[i] = csh[i];

#pragma unroll
    for (int it = 0; it < CHUNKS; ++it) {
        floatx4 r;
#pragma unroll
        for (int c = 0; c < 4; ++c) {
            const float xi = (&xv[it].x)[c];
            const float xp = __builtin_amdgcn_fmed3f(
                xi * 0.57735026918962576f, 0.0f, 0.9999f);
            int kk = 0;
            float tk = 0.f;
#pragma unroll
            for (int i = 0; i < 6; ++i) {
                if (xp >= cs[i]) { kk = i + 1; tk = cs[i]; }
            }
            const float s = xp - tk;
            const float4 cf = tbl[kk];
            r[c] = fmaf(fmaf(fmaf(cf.w, s, cf.z), s, cf.y), s, cf.x);
        }
        __builtin_nontemporal_store(
            r, reinterpret_cast<floatx4*>(&out[base + it * stride]));
    }
}

extern "C" void kernel_launch(void* const* d_in, const int* in_sizes, int n_in,
                              void* d_out, int out_size, void* d_ws, size_t ws_size,
                              hipStream_t stream) {
    const float* x  = (const float*)d_in[0];
    const float* a  = (const float*)d_in[1];
    const float* W1 = (const float*)d_in[2];
    const float* b1 = (const float*)d_in[3];
    const float* W2 = (const float*)d_in[4];
    const float* b2 = (const float*)d_in[5];
    const float* Ww = (const float*)d_in[6];
    const float* bw = (const float*)d_in[7];
    const float* Wk = (const float*)d_in[8];
    const float* bk = (const float*)d_in[9];
    float* out = (float*)d_out;

    const int n4 = out_size / 4;            // 256^3/4 = 4,194,304
    const int blocks = n4 / (256 * CHUNKS); // = 2048 persistent (8/CU)

    if (d_ws != nullptr && ws_size >= 34 * sizeof(float)) {
        float* ws = (float*)d_ws;
        nsff_table_kernel<<<1, 64, 0, stream>>>(ws, a, W1, b1, W2, b2,
                                                Ww, bw, Wk, bk);
        nsff_main_kernel<<<blocks, 256, 0, stream>>>((const float4*)x,
                                                     (float4*)out, ws);
    } else {
        nsff_fused_kernel<<<blocks, 256, 0, stream>>>((const float4*)x,
                                                      (float4*)out, a, W1, b1,
                                                      W2, b2, Ww, bw, Wk, bk);
    }
}